// Round 10
// baseline (37.779 us; speedup 1.0000x reference)
//
#include <hip/hip_runtime.h>
#include <cmath>
#include <complex>

// ChebyUpsample: x (256, 32768) f32 -> repeat x2 -> reverse -> cheby1(8,0.05,0.5)
// 4-biquad cascade -> reverse -> y (256, 65536) f32.
// Reversed-time chunked IIR, single-wave blocks, linear-predictor warm-up
// (R9 verified math), now GRID-STRIDED 2 tiles/block to break the phase
// convoy: block = 1 wave = 64 chunks x 32 inputs, tile = 2048 (+64 halo),
// 2048 blocks (8/CU, 2 waves/SIMD). Tile t1's global loads are ISSUED before
// t0's serial main compute (VMEM FIFO: loads predate t0's stores, so the
// staging vmcnt wait retires at most 1 store); t0's 64 fire-and-forget
// stores drain under t1's stage+compute instead of at kernel end.
// Zero barriers: all LDS hazards are same-wave (DS pipe is in-order).
// Predictor: z_main = sum_j w_j * staged[32l+32+j], w_j = A^{2j}(A+I)b
// (host double). Swizzle SWZ(q)=q^(((q>>6)&7)<<2): 16B-granular, bijective
// per 512-float window, identity in halo; stride-32 b128 reads at bank floor.

struct KArgs {
  float g;          // kz gain folded into staged input
  float a1[4];
  float a2[4];
  float w[64][8];   // state predictor taps, state order z10,z20,z11,...,z23
};

struct G2 { float4 a, b; };   // a = s[qq..qq+3], b = s[qq+4..qq+7]

#define SWZ(q) ((q) ^ ((((q) >> 6) & 7) << 2))

__global__ __launch_bounds__(64)
void cheby_up_kernel(const float* __restrict__ x, float* __restrict__ y, KArgs c) {
  constexpr int T_IN = 32768;
  constexpr int TILE = 2048;
  __shared__ __align__(16) float lbuf[TILE + 64];   // 8448 B

  const int row = blockIdx.x >> 3;
  const int pr  = blockIdx.x & 7;       // tile-pair index within row
  const int l   = threadIdx.x;          // lane = chunk id, 0..63
  const float* xrow = x + (size_t)row * T_IN;
  float*       yrow = y + (size_t)row * (size_t)(2 * T_IN);

  const float g = c.g;
  const float a10 = c.a1[0], a20 = c.a2[0];
  const float a11 = c.a1[1], a21 = c.a2[1];
  const float a12 = c.a1[2], a22 = c.a2[2];
  const float a13 = c.a1[3], a23 = c.a2[3];

  float4 r[8];                          // in-flight staging regs (next tile)
  float4 h;                             // in-flight halo

  auto issue_loads = [&](int tb) {      // issue only; consume later
    const float* src = xrow + TILE * tb;
    #pragma unroll
    for (int j = 0; j < 8; ++j)
      r[j] = *reinterpret_cast<const float4*>(src + 4 * l + 256 * j);
    h = make_float4(0.f, 0.f, 0.f, 0.f);
    const int gi = TILE * (tb + 1) + 4 * l;
    if (l < 16 && gi < T_IN)
      h = *reinterpret_cast<const float4*>(xrow + gi);
  };

  auto write_stage = [&]() {            // scale by g, swizzled ds_write
    #pragma unroll
    for (int j = 0; j < 8; ++j) {
      const int q = 4 * l + 256 * j;
      float4 v = r[j];
      v.x *= g; v.y *= g; v.z *= g; v.w *= g;
      *reinterpret_cast<float4*>(&lbuf[SWZ(q)]) = v;
    }
    if (l < 16) {
      float4 v = h;
      v.x *= g; v.y *= g; v.z *= g; v.w *= g;
      *reinterpret_cast<float4*>(&lbuf[TILE + 4 * l]) = v;  // SWZ identity
    }
  };

  auto rd8 = [&](int qq) -> G2 {        // 8 consecutive staged samples
    G2 v;
    v.a = *reinterpret_cast<const float4*>(&lbuf[SWZ(qq)]);
    v.b = *reinterpret_cast<const float4*>(&lbuf[SWZ(qq + 4)]);
    return v;
  };

  auto process_tile = [&](int tb, int nxt) {   // nxt<0: no prefetch
    // own 32 inputs -> registers
    G2 g3 = rd8(32 * l + 24);
    G2 g2 = rd8(32 * l + 16);
    G2 g1 = rd8(32 * l + 8);
    G2 g0 = rd8(32 * l);

    // prefetch next tile's loads NOW: before the serial main compute, and
    // before any of this tile's stores enter the VMEM FIFO
    if (nxt >= 0) issue_loads(nxt);

    // ---- linear-predictor warm-up over staged[32l+32 .. 32l+96) ----
    float ac0=0.f, ac1=0.f, ac2=0.f, ac3=0.f, ac4=0.f, ac5=0.f, ac6=0.f, ac7=0.f;
    #define TAP(jj, xx)                      \
      ac0 = fmaf(c.w[jj][0], (xx), ac0);     \
      ac1 = fmaf(c.w[jj][1], (xx), ac1);     \
      ac2 = fmaf(c.w[jj][2], (xx), ac2);     \
      ac3 = fmaf(c.w[jj][3], (xx), ac3);     \
      ac4 = fmaf(c.w[jj][4], (xx), ac4);     \
      ac5 = fmaf(c.w[jj][5], (xx), ac5);     \
      ac6 = fmaf(c.w[jj][6], (xx), ac6);     \
      ac7 = fmaf(c.w[jj][7], (xx), ac7);
    #pragma unroll
    for (int wg = 0; wg < 8; ++wg) {
      G2 v = rd8(32 * l + 32 + 8 * wg);
      const int j0 = 8 * wg;               // constant after unroll
      TAP(j0 + 0, v.a.x); TAP(j0 + 1, v.a.y);
      TAP(j0 + 2, v.a.z); TAP(j0 + 3, v.a.w);
      TAP(j0 + 4, v.b.x); TAP(j0 + 5, v.b.y);
      TAP(j0 + 6, v.b.z); TAP(j0 + 7, v.b.w);
    }
    #undef TAP

    // transposed direct-form II states seeded by the predictor
    float z10=ac0, z20=ac1, z11=ac2, z21=ac3;
    float z12=ac4, z22=ac5, z13=ac6, z23=ac7;

    auto step = [&](float x0) -> float {
      float y0 = x0 + z10;
      z10 = fmaf(-a10, y0, fmaf(2.f, x0, z20));
      z20 = fmaf(-a20, y0, x0);
      float y1 = y0 + z11;
      z11 = fmaf(-a11, y1, fmaf(2.f, y0, z21));
      z21 = fmaf(-a21, y1, y0);
      float y2 = y1 + z12;
      z12 = fmaf(-a12, y2, fmaf(2.f, y1, z22));
      z22 = fmaf(-a22, y2, y1);
      float y3 = y2 + z13;
      z13 = fmaf(-a13, y3, fmaf(2.f, y2, z23));
      z23 = fmaf(-a23, y3, y2);
      return y3;
    };

    float o[32];                         // static indices only

    auto flush32 = [&](int half) {       // per-wave transpose + dense stores
      #pragma unroll
      for (int i = 0; i < 8; ++i) {
        int q = 32 * l + 4 * i;
        *reinterpret_cast<float4*>(&lbuf[SWZ(q)]) =
            make_float4(o[4*i], o[4*i+1], o[4*i+2], o[4*i+3]);
      }
      float* yG = yrow + 2 * TILE * tb + half;
      #pragma unroll
      for (int j = 0; j < 8; ++j) {
        int local = 4 * l + 256 * j;                  // 0..2047
        float4 v = *reinterpret_cast<const float4*>(&lbuf[SWZ(local)]);
        int c64 = local >> 5;                         // source chunk 0..63
        int m   = local & 31;                         // offset within half
        *reinterpret_cast<float4*>(yG + 64 * c64 + m) = v;  // 128B dense runs
      }
    };

    // ---- phase A: outputs [32,64) from inputs [16,32) (forward descending)
    {
      float s;
      s = g3.b.w; o[31] = step(s); o[30] = step(s);
      s = g3.b.z; o[29] = step(s); o[28] = step(s);
      s = g3.b.y; o[27] = step(s); o[26] = step(s);
      s = g3.b.x; o[25] = step(s); o[24] = step(s);
      s = g3.a.w; o[23] = step(s); o[22] = step(s);
      s = g3.a.z; o[21] = step(s); o[20] = step(s);
      s = g3.a.y; o[19] = step(s); o[18] = step(s);
      s = g3.a.x; o[17] = step(s); o[16] = step(s);
      s = g2.b.w; o[15] = step(s); o[14] = step(s);
      s = g2.b.z; o[13] = step(s); o[12] = step(s);
      s = g2.b.y; o[11] = step(s); o[10] = step(s);
      s = g2.b.x; o[9]  = step(s); o[8]  = step(s);
      s = g2.a.w; o[7]  = step(s); o[6]  = step(s);
      s = g2.a.z; o[5]  = step(s); o[4]  = step(s);
      s = g2.a.y; o[3]  = step(s); o[2]  = step(s);
      s = g2.a.x; o[1]  = step(s); o[0]  = step(s);
    }
    flush32(32);

    // ---- phase B: outputs [0,32) from inputs [0,16) ----
    {
      float s;
      s = g1.b.w; o[31] = step(s); o[30] = step(s);
      s = g1.b.z; o[29] = step(s); o[28] = step(s);
      s = g1.b.y; o[27] = step(s); o[26] = step(s);
      s = g1.b.x; o[25] = step(s); o[24] = step(s);
      s = g1.a.w; o[23] = step(s); o[22] = step(s);
      s = g1.a.z; o[21] = step(s); o[20] = step(s);
      s = g1.a.y; o[19] = step(s); o[18] = step(s);
      s = g1.a.x; o[17] = step(s); o[16] = step(s);
      s = g0.b.w; o[15] = step(s); o[14] = step(s);
      s = g0.b.z; o[13] = step(s); o[12] = step(s);
      s = g0.b.y; o[11] = step(s); o[10] = step(s);
      s = g0.b.x; o[9]  = step(s); o[8]  = step(s);
      s = g0.a.w; o[7]  = step(s); o[6]  = step(s);
      s = g0.a.z; o[5]  = step(s); o[4]  = step(s);
      s = g0.a.y; o[3]  = step(s); o[2]  = step(s);
      s = g0.a.x; o[1]  = step(s); o[0]  = step(s);
    }
    flush32(0);

    // restage for next tile: ds_writes are same-wave in-order after flush
    // ds_reads; vmcnt wait for loads retires at most 1 store (FIFO).
    if (nxt >= 0) write_stage();
  };

  const int tb0 = 2 * pr;
  issue_loads(tb0);
  write_stage();
  process_tile(tb0, tb0 + 1);
  process_tile(tb0 + 1, -1);
}

// ---------------- host side ----------------

// one filter step in double, state order z10,z20,z11,z21,z12,z22,z13,z23
static void step_d(double z[8], double xx, const double A1[4], const double A2[4]) {
  double u = xx;
  double v = u + z[0];
  double n0 = 2.0*u - A1[0]*v + z[1];
  double n1 = u - A2[0]*v;
  u = v; v = u + z[2];
  double n2 = 2.0*u - A1[1]*v + z[3];
  double n3 = u - A2[1]*v;
  u = v; v = u + z[4];
  double n4 = 2.0*u - A1[2]*v + z[5];
  double n5 = u - A2[2]*v;
  u = v; v = u + z[6];
  double n6 = 2.0*u - A1[3]*v + z[7];
  double n7 = u - A2[3]*v;
  z[0]=n0; z[1]=n1; z[2]=n2; z[3]=n3; z[4]=n4; z[5]=n5; z[6]=n6; z[7]=n7;
}

static void matvec8(const double A[8][8], const double v[8], double out[8]) {
  for (int r = 0; r < 8; ++r) {
    double s = 0.0;
    for (int k = 0; k < 8; ++k) s += A[r][k] * v[k];
    out[r] = s;
  }
}

// Replicates _cheby1_sos(8, 0.05, 0.5) and builds predictor taps.
static KArgs compute_args() {
  const int N = 8;
  const double rp = 0.05, Wn = 0.5;
  const double PI = 3.14159265358979323846;
  double eps = std::sqrt(std::pow(10.0, 0.1 * rp) - 1.0);
  double mu = std::asinh(1.0 / eps) / (double)N;
  std::complex<double> p[8];
  std::complex<double> prodNegP(1.0, 0.0);
  int idx = 0;
  for (int m = -N + 1; m < N; m += 2) {
    double theta = PI * (double)m / (2.0 * N);
    std::complex<double> pp = -std::sinh(std::complex<double>(mu, theta));
    p[idx++] = pp;
    prodNegP *= -pp;
  }
  double k = prodNegP.real();
  k /= std::sqrt(1.0 + eps * eps);          // even N
  const double fs = 2.0;
  double warped = 2.0 * fs * std::tan(PI * Wn / fs);
  for (int i = 0; i < 8; i++) p[i] *= warped;
  k *= std::pow(warped, (double)N);
  const double fs2 = 2.0 * fs;
  std::complex<double> prodDen(1.0, 0.0);
  for (int i = 0; i < 8; i++) prodDen *= (fs2 - p[i]);
  double kz = k * (1.0 / prodDen).real();

  KArgs c;
  double A1d[4], A2d[4];
  int s = 0;
  for (int i = 0; i < 8; i++) {
    std::complex<double> pz = (fs2 + p[i]) / (fs2 - p[i]);
    if (pz.imag() > 0.0) {                  // same selection order as numpy
      A1d[s] = -2.0 * pz.real();
      A2d[s] = std::norm(pz);               // |pz|^2
      c.a1[s] = (float)A1d[s];
      c.a2[s] = (float)A2d[s];
      s++;
    }
  }
  c.g = (float)kz;

  // build A (8x8) and b from the step function
  double A[8][8], bv[8];
  for (int i = 0; i < 8; ++i) {
    double z[8] = {0,0,0,0,0,0,0,0};
    z[i] = 1.0;
    step_d(z, 0.0, A1d, A2d);
    for (int r = 0; r < 8; ++r) A[r][i] = z[r];
  }
  {
    double z[8] = {0,0,0,0,0,0,0,0};
    step_d(z, 1.0, A1d, A2d);
    for (int r = 0; r < 8; ++r) bv[r] = z[r];
  }
  // w_0 = (A+I)b ; w_{j+1} = A^2 w_j
  double w[8], t[8];
  matvec8(A, bv, t);
  for (int r = 0; r < 8; ++r) w[r] = t[r] + bv[r];
  for (int j = 0; j < 64; ++j) {
    for (int r = 0; r < 8; ++r) c.w[j][r] = (float)w[r];
    matvec8(A, w, t);
    matvec8(A, t, w);
  }
  return c;
}

extern "C" void kernel_launch(void* const* d_in, const int* in_sizes, int n_in,
                              void* d_out, int out_size, void* d_ws, size_t ws_size,
                              hipStream_t stream) {
  const float* x = (const float*)d_in[0];
  float* y = (float*)d_out;
  KArgs c = compute_args();
  int rows = in_sizes[0] / 32768;   // 256
  // 8 tile-pairs per row -> 2048 single-wave blocks, 2 tiles each
  cheby_up_kernel<<<8 * rows, 64, 0, stream>>>(x, y, c);
}

// Round 11
// 31.671 us; speedup vs baseline: 1.1929x; 1.1929x over previous
//
#include <hip/hip_runtime.h>
#include <cmath>
#include <complex>

// ChebyUpsample: x (256, 32768) f32 -> repeat x2 -> reverse -> cheby1(8,0.05,0.5)
// 4-biquad cascade -> reverse -> y (256, 65536) f32.
// Reversed-time chunked IIR, single-wave blocks, linear-predictor warm-up.
// R11: chunk = 16 inputs/lane (tile = 1024 + 64 halo), 8192 blocks.
//   LDS = 9216B/block (flush needs 2048 floats) -> <=17 blocks/CU resident
//   -> ~2 sequential block generations per CU: gen-2's read+compute overlaps
//   gen-1's 32MB store drain (R9 = exactly 1 generation = phase convoy).
//   Each generation keeps 4+ waves/SIMD (hard requirement learned in R7/R10:
//   the serial IIR dep chain needs >=4 waves/SIMD to hide).
// Predictor: z_main = sum_{j=0..63} w_j * staged[chunk_end + j], w_j =
// A^{2j}(A+I)b (host double) -> 512 independent FMAs replace 128 serial steps.
// Zero barriers: single wave per block, DS pipe is in-order.
// Swizzle SWZ(q)=q^(((q>>6)&7)<<2): 16B-granular, bijective per 512-float
// window, identity in halo [1024,1088); stride-16 b128 reads ~4-way aliased.

struct KArgs {
  float g;          // kz gain folded into staged input
  float a1[4];
  float a2[4];
  float w[64][8];   // state predictor taps, state order z10,z20,z11,...,z23
};

struct G2 { float4 a, b; };   // a = s[qq..qq+3], b = s[qq+4..qq+7]

#define SWZ(q) ((q) ^ ((((q) >> 6) & 7) << 2))

__global__ __launch_bounds__(64)
void cheby_up_kernel(const float* __restrict__ x, float* __restrict__ y, KArgs c) {
  constexpr int T_IN = 32768;
  constexpr int TILE = 1024;
  // [0,1088) staged input+halo; flush reuses [0,2048); 2304 floats = 9216B
  // deliberately caps residency at ~17 blocks/CU -> ~2 generations.
  __shared__ __align__(16) float lbuf[2304];

  const int row = blockIdx.x >> 5;
  const int tb  = blockIdx.x & 31;      // tile index within row, 0..31
  const int l   = threadIdx.x;          // lane = chunk id, 0..63
  const float* xrow = x + (size_t)row * T_IN;
  float*       yrow = y + (size_t)row * (size_t)(2 * T_IN);
  const int tbase = TILE * tb;

  const float g = c.g;

  // ---- stage tile, coalesced, pre-scaled by g (4 x float4 per lane) ----
  #pragma unroll
  for (int j = 0; j < 4; ++j) {
    int q = 4 * l + 256 * j;                        // 0..1023
    float4 v = *reinterpret_cast<const float4*>(xrow + tbase + q);
    v.x *= g; v.y *= g; v.z *= g; v.w *= g;
    *reinterpret_cast<float4*>(&lbuf[SWZ(q)]) = v;
  }
  if (l < 16) {                                     // 64-float halo
    int q = TILE + 4 * l;                           // 1024..1087, SWZ identity
    int gi = tbase + q;
    float4 v = make_float4(0.f, 0.f, 0.f, 0.f);
    if (gi < T_IN) {
      v = *reinterpret_cast<const float4*>(xrow + gi);
      v.x *= g; v.y *= g; v.z *= g; v.w *= g;
    }
    *reinterpret_cast<float4*>(&lbuf[q]) = v;
  }
  // single wave: DS reads below are ordered after these writes (lgkmcnt)

  auto rd8 = [&](int qq) -> G2 {        // 8 consecutive staged samples
    G2 v;
    v.a = *reinterpret_cast<const float4*>(&lbuf[SWZ(qq)]);
    v.b = *reinterpret_cast<const float4*>(&lbuf[SWZ(qq + 4)]);
    return v;
  };

  // own 16 inputs -> registers (issued before taps; independent)
  G2 g1 = rd8(16 * l + 8);
  G2 g0 = rd8(16 * l);

  // ---- linear-predictor warm-up over staged[16l+16 .. 16l+80) ----
  float ac0=0.f, ac1=0.f, ac2=0.f, ac3=0.f, ac4=0.f, ac5=0.f, ac6=0.f, ac7=0.f;
  #define TAP(jj, xx)                      \
    ac0 = fmaf(c.w[jj][0], (xx), ac0);     \
    ac1 = fmaf(c.w[jj][1], (xx), ac1);     \
    ac2 = fmaf(c.w[jj][2], (xx), ac2);     \
    ac3 = fmaf(c.w[jj][3], (xx), ac3);     \
    ac4 = fmaf(c.w[jj][4], (xx), ac4);     \
    ac5 = fmaf(c.w[jj][5], (xx), ac5);     \
    ac6 = fmaf(c.w[jj][6], (xx), ac6);     \
    ac7 = fmaf(c.w[jj][7], (xx), ac7);
  #pragma unroll
  for (int wg = 0; wg < 8; ++wg) {
    G2 v = rd8(16 * l + 16 + 8 * wg);
    const int j0 = 8 * wg;                 // constant after unroll
    TAP(j0 + 0, v.a.x); TAP(j0 + 1, v.a.y);
    TAP(j0 + 2, v.a.z); TAP(j0 + 3, v.a.w);
    TAP(j0 + 4, v.b.x); TAP(j0 + 5, v.b.y);
    TAP(j0 + 6, v.b.z); TAP(j0 + 7, v.b.w);
  }
  #undef TAP

  const float a10 = c.a1[0], a20 = c.a2[0];
  const float a11 = c.a1[1], a21 = c.a2[1];
  const float a12 = c.a1[2], a22 = c.a2[2];
  const float a13 = c.a1[3], a23 = c.a2[3];

  // transposed direct-form II states seeded by the predictor
  float z10=ac0, z20=ac1, z11=ac2, z21=ac3;
  float z12=ac4, z22=ac5, z13=ac6, z23=ac7;

  auto step = [&](float x0) -> float {
    float y0 = x0 + z10;
    z10 = fmaf(-a10, y0, fmaf(2.f, x0, z20));
    z20 = fmaf(-a20, y0, x0);
    float y1 = y0 + z11;
    z11 = fmaf(-a11, y1, fmaf(2.f, y0, z21));
    z21 = fmaf(-a21, y1, y0);
    float y2 = y1 + z12;
    z12 = fmaf(-a12, y2, fmaf(2.f, y1, z22));
    z22 = fmaf(-a22, y2, y1);
    float y3 = y2 + z13;
    z13 = fmaf(-a13, y3, fmaf(2.f, y2, z23));
    z23 = fmaf(-a23, y3, y2);
    return y3;
  };

  // ---- main: 16 inputs (forward descending) -> 32 outputs ----
  // input at local offset k yields forward outputs 2k+1 then 2k
  float o[32];                           // static indices only
  {
    float s;
    s = g1.b.w; o[31] = step(s); o[30] = step(s);
    s = g1.b.z; o[29] = step(s); o[28] = step(s);
    s = g1.b.y; o[27] = step(s); o[26] = step(s);
    s = g1.b.x; o[25] = step(s); o[24] = step(s);
    s = g1.a.w; o[23] = step(s); o[22] = step(s);
    s = g1.a.z; o[21] = step(s); o[20] = step(s);
    s = g1.a.y; o[19] = step(s); o[18] = step(s);
    s = g1.a.x; o[17] = step(s); o[16] = step(s);
    s = g0.b.w; o[15] = step(s); o[14] = step(s);
    s = g0.b.z; o[13] = step(s); o[12] = step(s);
    s = g0.b.y; o[11] = step(s); o[10] = step(s);
    s = g0.b.x; o[9]  = step(s); o[8]  = step(s);
    s = g0.a.w; o[7]  = step(s); o[6]  = step(s);
    s = g0.a.z; o[5]  = step(s); o[4]  = step(s);
    s = g0.a.y; o[3]  = step(s); o[2]  = step(s);
    s = g0.a.x; o[1]  = step(s); o[0]  = step(s);
  }

  // ---- flush: per-wave transpose through lbuf[0,2048), 128B-dense stores ----
  // (same-wave DS ordering; all staged reads above already consumed)
  #pragma unroll
  for (int i = 0; i < 8; ++i) {
    int q = 32 * l + 4 * i;
    *reinterpret_cast<float4*>(&lbuf[SWZ(q)]) =
        make_float4(o[4*i], o[4*i+1], o[4*i+2], o[4*i+3]);
  }
  float* yG = yrow + 2 * tbase;
  #pragma unroll
  for (int j = 0; j < 8; ++j) {
    int local = 4 * l + 256 * j;                    // 0..2047
    float4 v = *reinterpret_cast<const float4*>(&lbuf[SWZ(local)]);
    int c64 = local >> 5;                           // source chunk 0..63
    int m   = local & 31;                           // offset within chunk run
    *reinterpret_cast<float4*>(yG + 32 * c64 + m) = v;   // 128B dense runs
  }
}

// ---------------- host side ----------------

// one filter step in double, state order z10,z20,z11,z21,z12,z22,z13,z23
static void step_d(double z[8], double xx, const double A1[4], const double A2[4]) {
  double u = xx;
  double v = u + z[0];
  double n0 = 2.0*u - A1[0]*v + z[1];
  double n1 = u - A2[0]*v;
  u = v; v = u + z[2];
  double n2 = 2.0*u - A1[1]*v + z[3];
  double n3 = u - A2[1]*v;
  u = v; v = u + z[4];
  double n4 = 2.0*u - A1[2]*v + z[5];
  double n5 = u - A2[2]*v;
  u = v; v = u + z[6];
  double n6 = 2.0*u - A1[3]*v + z[7];
  double n7 = u - A2[3]*v;
  z[0]=n0; z[1]=n1; z[2]=n2; z[3]=n3; z[4]=n4; z[5]=n5; z[6]=n6; z[7]=n7;
}

static void matvec8(const double A[8][8], const double v[8], double out[8]) {
  for (int r = 0; r < 8; ++r) {
    double s = 0.0;
    for (int k = 0; k < 8; ++k) s += A[r][k] * v[k];
    out[r] = s;
  }
}

// Replicates _cheby1_sos(8, 0.05, 0.5) and builds predictor taps.
static KArgs compute_args() {
  const int N = 8;
  const double rp = 0.05, Wn = 0.5;
  const double PI = 3.14159265358979323846;
  double eps = std::sqrt(std::pow(10.0, 0.1 * rp) - 1.0);
  double mu = std::asinh(1.0 / eps) / (double)N;
  std::complex<double> p[8];
  std::complex<double> prodNegP(1.0, 0.0);
  int idx = 0;
  for (int m = -N + 1; m < N; m += 2) {
    double theta = PI * (double)m / (2.0 * N);
    std::complex<double> pp = -std::sinh(std::complex<double>(mu, theta));
    p[idx++] = pp;
    prodNegP *= -pp;
  }
  double k = prodNegP.real();
  k /= std::sqrt(1.0 + eps * eps);          // even N
  const double fs = 2.0;
  double warped = 2.0 * fs * std::tan(PI * Wn / fs);
  for (int i = 0; i < 8; i++) p[i] *= warped;
  k *= std::pow(warped, (double)N);
  const double fs2 = 2.0 * fs;
  std::complex<double> prodDen(1.0, 0.0);
  for (int i = 0; i < 8; i++) prodDen *= (fs2 - p[i]);
  double kz = k * (1.0 / prodDen).real();

  KArgs c;
  double A1d[4], A2d[4];
  int s = 0;
  for (int i = 0; i < 8; i++) {
    std::complex<double> pz = (fs2 + p[i]) / (fs2 - p[i]);
    if (pz.imag() > 0.0) {                  // same selection order as numpy
      A1d[s] = -2.0 * pz.real();
      A2d[s] = std::norm(pz);               // |pz|^2
      c.a1[s] = (float)A1d[s];
      c.a2[s] = (float)A2d[s];
      s++;
    }
  }
  c.g = (float)kz;

  // build A (8x8) and b from the step function
  double A[8][8], bv[8];
  for (int i = 0; i < 8; ++i) {
    double z[8] = {0,0,0,0,0,0,0,0};
    z[i] = 1.0;
    step_d(z, 0.0, A1d, A2d);
    for (int r = 0; r < 8; ++r) A[r][i] = z[r];
  }
  {
    double z[8] = {0,0,0,0,0,0,0,0};
    step_d(z, 1.0, A1d, A2d);
    for (int r = 0; r < 8; ++r) bv[r] = z[r];
  }
  // w_0 = (A+I)b ; w_{j+1} = A^2 w_j
  double w[8], t[8];
  matvec8(A, bv, t);
  for (int r = 0; r < 8; ++r) w[r] = t[r] + bv[r];
  for (int j = 0; j < 64; ++j) {
    for (int r = 0; r < 8; ++r) c.w[j][r] = (float)w[r];
    matvec8(A, w, t);
    matvec8(A, t, w);
  }
  return c;
}

extern "C" void kernel_launch(void* const* d_in, const int* in_sizes, int n_in,
                              void* d_out, int out_size, void* d_ws, size_t ws_size,
                              hipStream_t stream) {
  const float* x = (const float*)d_in[0];
  float* y = (float*)d_out;
  KArgs c = compute_args();
  int rows = in_sizes[0] / 32768;   // 256
  // 32 single-wave tiles per row -> 8192 blocks of 64 threads (~2 generations)
  cheby_up_kernel<<<32 * rows, 64, 0, stream>>>(x, y, c);
}

// Round 14
// 27.354 us; speedup vs baseline: 1.3811x; 1.1578x over previous
//
#include <hip/hip_runtime.h>
#include <cmath>
#include <complex>

// ChebyUpsample: x (256, 32768) f32 -> repeat x2 -> reverse -> cheby1(8,0.05,0.5)
// 4-biquad cascade -> reverse -> y (256, 65536) f32.
// R9-verified kernel (reversed-time chunked IIR, single-wave blocks, linear-
// predictor warm-up) + PER-BLOCK START STAGGER to break the phase convoy:
//   delay class d = (blockIdx.x >> 8) & 15 -> d x ~0.64us s_sleep before any
//   load issues. 16 classes x 256 blocks: each class ~1 block/CU, class order
//   matches dispatch order. Co-resident waves then sit in DIFFERENT phases
//   (reads / compute / store drain) -> HBM demand flattens toward the 96MB
//   floor instead of sum-of-phases bursts. Sleep is semantically a no-op:
//   kernel is otherwise byte-identical to the verified R9 (absmax 0.015625).
// Structure: block = 1 wave = 64 chunks x 32 inputs; tile = 2048 (+64 halo)
// = 8448B LDS; 4096 blocks = 16/CU = 4 waves/SIMD. Zero barriers (single
// wave; DS pipe in-order). Predictor: z = sum_{j=0..63} w_j*staged[32l+32+j],
// w_j = A^{2j}(A+I)b (host double). Flush: per-wave transpose through the
// dead input region, 2 halves, 128B-dense stores.
// SWZ(q)=q^(((q>>6)&7)<<2): 16B-granular involution, identity in halo.

struct KArgs {
  float g;          // kz gain folded into staged input
  float a1[4];
  float a2[4];
  float w[64][8];   // state predictor taps, state order z10,z20,z11,...,z23
};

struct G2 { float4 a, b; };   // a = s[qq..qq+3], b = s[qq+4..qq+7]

#define SWZ(q) ((q) ^ ((((q) >> 6) & 7) << 2))

__global__ __launch_bounds__(64)
void cheby_up_kernel(const float* __restrict__ x, float* __restrict__ y, KArgs c) {
  constexpr int T_IN = 32768;
  constexpr int TILE = 2048;
  __shared__ __align__(16) float lbuf[TILE + 64];   // 8448 B

  // ---- start stagger: delay class = dispatch-order chunk of 256 blocks ----
  {
    const int d = (blockIdx.x >> 8) & 15;
    for (int i = 0; i < d; ++i)
      __builtin_amdgcn_s_sleep(24);   // 24*64 = 1536 cyc ~= 0.64 us per unit
  }

  const int row = blockIdx.x >> 4;
  const int tb  = blockIdx.x & 15;      // tile index within row
  const int l   = threadIdx.x;          // lane = chunk id, 0..63
  const float* xrow = x + (size_t)row * T_IN;
  float*       yrow = y + (size_t)row * (size_t)(2 * T_IN);
  const int tbase = TILE * tb;

  const float g = c.g;

  // ---- stage tile, coalesced, pre-scaled by g (8 x float4 per lane) ----
  #pragma unroll
  for (int j = 0; j < 8; ++j) {
    int q = 4 * l + 256 * j;                        // 0..2047
    float4 v = *reinterpret_cast<const float4*>(xrow + tbase + q);
    v.x *= g; v.y *= g; v.z *= g; v.w *= g;
    *reinterpret_cast<float4*>(&lbuf[SWZ(q)]) = v;
  }
  if (l < 16) {                                     // 64-float halo
    int q = TILE + 4 * l;                           // SWZ identity here
    int gi = tbase + q;
    float4 v = make_float4(0.f, 0.f, 0.f, 0.f);
    if (gi < T_IN) {
      v = *reinterpret_cast<const float4*>(xrow + gi);
      v.x *= g; v.y *= g; v.z *= g; v.w *= g;
    }
    *reinterpret_cast<float4*>(&lbuf[q]) = v;
  }
  // single wave: DS reads below are ordered after these writes (lgkmcnt)

  auto rd8 = [&](int qq) -> G2 {        // 8 consecutive staged samples
    G2 r;
    r.a = *reinterpret_cast<const float4*>(&lbuf[SWZ(qq)]);
    r.b = *reinterpret_cast<const float4*>(&lbuf[SWZ(qq + 4)]);
    return r;
  };

  // own 32 inputs -> registers (independent of warm region; issue early)
  G2 g3 = rd8(32 * l + 24);
  G2 g2 = rd8(32 * l + 16);
  G2 g1 = rd8(32 * l + 8);
  G2 g0 = rd8(32 * l);

  // ---- linear-predictor warm-up: z = sum_{j=0..63} w_j * staged[32l+32+j] ----
  float ac0=0.f, ac1=0.f, ac2=0.f, ac3=0.f, ac4=0.f, ac5=0.f, ac6=0.f, ac7=0.f;
  #define TAP(jj, xx)                      \
    ac0 = fmaf(c.w[jj][0], (xx), ac0);     \
    ac1 = fmaf(c.w[jj][1], (xx), ac1);     \
    ac2 = fmaf(c.w[jj][2], (xx), ac2);     \
    ac3 = fmaf(c.w[jj][3], (xx), ac3);     \
    ac4 = fmaf(c.w[jj][4], (xx), ac4);     \
    ac5 = fmaf(c.w[jj][5], (xx), ac5);     \
    ac6 = fmaf(c.w[jj][6], (xx), ac6);     \
    ac7 = fmaf(c.w[jj][7], (xx), ac7);
  #pragma unroll
  for (int wg = 0; wg < 8; ++wg) {
    G2 v = rd8(32 * l + 32 + 8 * wg);
    const int j0 = 8 * wg;                 // constant after unroll
    TAP(j0 + 0, v.a.x); TAP(j0 + 1, v.a.y);
    TAP(j0 + 2, v.a.z); TAP(j0 + 3, v.a.w);
    TAP(j0 + 4, v.b.x); TAP(j0 + 5, v.b.y);
    TAP(j0 + 6, v.b.z); TAP(j0 + 7, v.b.w);
  }
  #undef TAP

  const float a10 = c.a1[0], a20 = c.a2[0];
  const float a11 = c.a1[1], a21 = c.a2[1];
  const float a12 = c.a1[2], a22 = c.a2[2];
  const float a13 = c.a1[3], a23 = c.a2[3];

  // transposed direct-form II states seeded by the predictor
  float z10=ac0, z20=ac1, z11=ac2, z21=ac3;
  float z12=ac4, z22=ac5, z13=ac6, z23=ac7;

  auto step = [&](float x0) -> float {
    float y0 = x0 + z10;
    z10 = fmaf(-a10, y0, fmaf(2.f, x0, z20));
    z20 = fmaf(-a20, y0, x0);
    float y1 = y0 + z11;
    z11 = fmaf(-a11, y1, fmaf(2.f, y0, z21));
    z21 = fmaf(-a21, y1, y0);
    float y2 = y1 + z12;
    z12 = fmaf(-a12, y2, fmaf(2.f, y1, z22));
    z22 = fmaf(-a22, y2, y1);
    float y3 = y2 + z13;
    z13 = fmaf(-a13, y3, fmaf(2.f, y2, z23));
    z23 = fmaf(-a23, y3, y2);
    return y3;
  };

  float o[32];                // static indices only (fully unrolled)

  // per-wave transpose+store of 32 outputs at chunk offset `half`
  auto flush32 = [&](int half) {
    #pragma unroll
    for (int i = 0; i < 8; ++i) {
      int q = 32 * l + 4 * i;
      *reinterpret_cast<float4*>(&lbuf[SWZ(q)]) =
          make_float4(o[4*i], o[4*i+1], o[4*i+2], o[4*i+3]);
    }
    float* yG = yrow + 2 * tbase + half;
    #pragma unroll
    for (int j = 0; j < 8; ++j) {
      int local = 4 * l + 256 * j;                    // 0..2047
      float4 v = *reinterpret_cast<const float4*>(&lbuf[SWZ(local)]);
      int c64 = local >> 5;                           // source chunk 0..63
      int m   = local & 31;                           // offset within half
      *reinterpret_cast<float4*>(yG + 64 * c64 + m) = v;  // 128B dense runs
    }
  };

  // ---- phase A: outputs [32,64) from inputs [16,32) (forward descending) ----
  {
    float s;
    s = g3.b.w; o[31] = step(s); o[30] = step(s);
    s = g3.b.z; o[29] = step(s); o[28] = step(s);
    s = g3.b.y; o[27] = step(s); o[26] = step(s);
    s = g3.b.x; o[25] = step(s); o[24] = step(s);
    s = g3.a.w; o[23] = step(s); o[22] = step(s);
    s = g3.a.z; o[21] = step(s); o[20] = step(s);
    s = g3.a.y; o[19] = step(s); o[18] = step(s);
    s = g3.a.x; o[17] = step(s); o[16] = step(s);
    s = g2.b.w; o[15] = step(s); o[14] = step(s);
    s = g2.b.z; o[13] = step(s); o[12] = step(s);
    s = g2.b.y; o[11] = step(s); o[10] = step(s);
    s = g2.b.x; o[9]  = step(s); o[8]  = step(s);
    s = g2.a.w; o[7]  = step(s); o[6]  = step(s);
    s = g2.a.z; o[5]  = step(s); o[4]  = step(s);
    s = g2.a.y; o[3]  = step(s); o[2]  = step(s);
    s = g2.a.x; o[1]  = step(s); o[0]  = step(s);
  }
  flush32(32);

  // ---- phase B: outputs [0,32) from inputs [0,16) ----
  {
    float s;
    s = g1.b.w; o[31] = step(s); o[30] = step(s);
    s = g1.b.z; o[29] = step(s); o[28] = step(s);
    s = g1.b.y; o[27] = step(s); o[26] = step(s);
    s = g1.b.x; o[25] = step(s); o[24] = step(s);
    s = g1.a.w; o[23] = step(s); o[22] = step(s);
    s = g1.a.z; o[21] = step(s); o[20] = step(s);
    s = g1.a.y; o[19] = step(s); o[18] = step(s);
    s = g1.a.x; o[17] = step(s); o[16] = step(s);
    s = g0.b.w; o[15] = step(s); o[14] = step(s);
    s = g0.b.z; o[13] = step(s); o[12] = step(s);
    s = g0.b.y; o[11] = step(s); o[10] = step(s);
    s = g0.b.x; o[9]  = step(s); o[8]  = step(s);
    s = g0.a.w; o[7]  = step(s); o[6]  = step(s);
    s = g0.a.z; o[5]  = step(s); o[4]  = step(s);
    s = g0.a.y; o[3]  = step(s); o[2]  = step(s);
    s = g0.a.x; o[1]  = step(s); o[0]  = step(s);
  }
  flush32(0);
}

// ---------------- host side ----------------

// one filter step in double, state order z10,z20,z11,z21,z12,z22,z13,z23
static void step_d(double z[8], double xx, const double A1[4], const double A2[4]) {
  double u = xx;
  double v = u + z[0];
  double n0 = 2.0*u - A1[0]*v + z[1];
  double n1 = u - A2[0]*v;
  u = v; v = u + z[2];
  double n2 = 2.0*u - A1[1]*v + z[3];
  double n3 = u - A2[1]*v;
  u = v; v = u + z[4];
  double n4 = 2.0*u - A1[2]*v + z[5];
  double n5 = u - A2[2]*v;
  u = v; v = u + z[6];
  double n6 = 2.0*u - A1[3]*v + z[7];
  double n7 = u - A2[3]*v;
  z[0]=n0; z[1]=n1; z[2]=n2; z[3]=n3; z[4]=n4; z[5]=n5; z[6]=n6; z[7]=n7;
}

static void matvec8(const double A[8][8], const double v[8], double out[8]) {
  for (int r = 0; r < 8; ++r) {
    double s = 0.0;
    for (int k = 0; k < 8; ++k) s += A[r][k] * v[k];
    out[r] = s;
  }
}

// Replicates _cheby1_sos(8, 0.05, 0.5) and builds predictor taps.
static KArgs compute_args() {
  const int N = 8;
  const double rp = 0.05, Wn = 0.5;
  const double PI = 3.14159265358979323846;
  double eps = std::sqrt(std::pow(10.0, 0.1 * rp) - 1.0);
  double mu = std::asinh(1.0 / eps) / (double)N;
  std::complex<double> p[8];
  std::complex<double> prodNegP(1.0, 0.0);
  int idx = 0;
  for (int m = -N + 1; m < N; m += 2) {
    double theta = PI * (double)m / (2.0 * N);
    std::complex<double> pp = -std::sinh(std::complex<double>(mu, theta));
    p[idx++] = pp;
    prodNegP *= -pp;
  }
  double k = prodNegP.real();
  k /= std::sqrt(1.0 + eps * eps);          // even N
  const double fs = 2.0;
  double warped = 2.0 * fs * std::tan(PI * Wn / fs);
  for (int i = 0; i < 8; i++) p[i] *= warped;
  k *= std::pow(warped, (double)N);
  const double fs2 = 2.0 * fs;
  std::complex<double> prodDen(1.0, 0.0);
  for (int i = 0; i < 8; i++) prodDen *= (fs2 - p[i]);
  double kz = k * (1.0 / prodDen).real();

  KArgs c;
  double A1d[4], A2d[4];
  int s = 0;
  for (int i = 0; i < 8; i++) {
    std::complex<double> pz = (fs2 + p[i]) / (fs2 - p[i]);
    if (pz.imag() > 0.0) {                  // same selection order as numpy
      A1d[s] = -2.0 * pz.real();
      A2d[s] = std::norm(pz);               // |pz|^2
      c.a1[s] = (float)A1d[s];
      c.a2[s] = (float)A2d[s];
      s++;
    }
  }
  c.g = (float)kz;

  // build A (8x8) and b from the step function
  double A[8][8], bv[8];
  for (int i = 0; i < 8; ++i) {
    double z[8] = {0,0,0,0,0,0,0,0};
    z[i] = 1.0;
    step_d(z, 0.0, A1d, A2d);
    for (int r = 0; r < 8; ++r) A[r][i] = z[r];
  }
  {
    double z[8] = {0,0,0,0,0,0,0,0};
    step_d(z, 1.0, A1d, A2d);
    for (int r = 0; r < 8; ++r) bv[r] = z[r];
  }
  // w_0 = (A+I)b ; w_{j+1} = A^2 w_j
  double w[8], t[8];
  matvec8(A, bv, t);
  for (int r = 0; r < 8; ++r) w[r] = t[r] + bv[r];
  for (int j = 0; j < 64; ++j) {
    for (int r = 0; r < 8; ++r) c.w[j][r] = (float)w[r];
    matvec8(A, w, t);
    matvec8(A, t, w);
  }
  return c;
}

extern "C" void kernel_launch(void* const* d_in, const int* in_sizes, int n_in,
                              void* d_out, int out_size, void* d_ws, size_t ws_size,
                              hipStream_t stream) {
  const float* x = (const float*)d_in[0];
  float* y = (float*)d_out;
  KArgs c = compute_args();
  int rows = in_sizes[0] / 32768;   // 256
  // 16 single-wave tiles per row -> 4096 blocks of 64 threads
  cheby_up_kernel<<<16 * rows, 64, 0, stream>>>(x, y, c);
}

// Round 15
// 26.865 us; speedup vs baseline: 1.4063x; 1.0182x over previous
//
#include <hip/hip_runtime.h>
#include <cmath>
#include <complex>

// ChebyUpsample: x (256, 32768) f32 -> repeat x2 -> reverse -> cheby1(8,0.05,0.5)
// 4-biquad cascade -> reverse -> y (256, 65536) f32.
// Reversed-time chunked IIR, single-wave blocks, linear-predictor warm-up.
// R15 = R11's verified math with LDS slimmed for occupancy:
//   chunk = 16 inputs/lane, tile = 1024 (+64 halo) = 1088 floats = 4.35KB LDS
//   (was 9.2KB). 8192 blocks; residency now VGPR-bound (~75 VGPR) ->
//   ~6 waves/SIMD vs R9's grid-limited 4 -> +50% TLP to fill the per-wave
//   memory-wait gaps (R14 stagger-null + VALUBusy 36% diagnosis).
//   Flush fits 1088 floats via 2 half-wave rounds: round r, lanes
//   [32r,32r+32) write their 32 outputs into L[0,1024); all lanes read back
//   lane-contiguous and store 128B-dense. Same-wave DS is in-order (HW);
//   sched_barrier(0) fences pin the compiler's DS ordering across phases.
// Predictor: z = sum_{j=0..63} w_j * staged[16l+16+j], w_j = A^{2j}(A+I)b
// (host double; staged pre-scaled by g, taps raw — R11-verified).
// SWZ(q)=q^(((q>>6)&7)<<2): 16B-granular involution within 512-float
// windows, identity in halo [1024,1088).

struct KArgs {
  float g;          // kz gain folded into staged input
  float a1[4];
  float a2[4];
  float w[64][8];   // state predictor taps, state order z10,z20,z11,...,z23
};

struct G2 { float4 a, b; };   // a = s[qq..qq+3], b = s[qq+4..qq+7]

#define SWZ(q) ((q) ^ ((((q) >> 6) & 7) << 2))

__global__ __launch_bounds__(64)
void cheby_up_kernel(const float* __restrict__ x, float* __restrict__ y, KArgs c) {
  constexpr int T_IN = 32768;
  constexpr int TILE = 1024;
  __shared__ __align__(16) float lbuf[TILE + 64];   // 4352 B

  const int row = blockIdx.x >> 5;
  const int tb  = blockIdx.x & 31;      // tile index within row, 0..31
  const int l   = threadIdx.x;          // lane = chunk id, 0..63
  const float* xrow = x + (size_t)row * T_IN;
  float*       yrow = y + (size_t)row * (size_t)(2 * T_IN);
  const int tbase = TILE * tb;

  const float g = c.g;

  // ---- stage tile, coalesced, pre-scaled by g (4 x float4 per lane) ----
  #pragma unroll
  for (int j = 0; j < 4; ++j) {
    int q = 4 * l + 256 * j;                        // 0..1023
    float4 v = *reinterpret_cast<const float4*>(xrow + tbase + q);
    v.x *= g; v.y *= g; v.z *= g; v.w *= g;
    *reinterpret_cast<float4*>(&lbuf[SWZ(q)]) = v;
  }
  if (l < 16) {                                     // 64-float halo
    int q = TILE + 4 * l;                           // 1024..1087, SWZ identity
    int gi = tbase + q;
    float4 v = make_float4(0.f, 0.f, 0.f, 0.f);
    if (gi < T_IN) {
      v = *reinterpret_cast<const float4*>(xrow + gi);
      v.x *= g; v.y *= g; v.z *= g; v.w *= g;
    }
    *reinterpret_cast<float4*>(&lbuf[q]) = v;
  }
  // single wave: DS reads below are ordered after these writes (lgkmcnt)

  auto rd8 = [&](int qq) -> G2 {        // 8 consecutive staged samples
    G2 v;
    v.a = *reinterpret_cast<const float4*>(&lbuf[SWZ(qq)]);
    v.b = *reinterpret_cast<const float4*>(&lbuf[SWZ(qq + 4)]);
    return v;
  };

  // own 16 inputs -> registers (issued before taps; independent)
  G2 g1 = rd8(16 * l + 8);
  G2 g0 = rd8(16 * l);

  // ---- linear-predictor warm-up over staged[16l+16 .. 16l+80) ----
  float ac0=0.f, ac1=0.f, ac2=0.f, ac3=0.f, ac4=0.f, ac5=0.f, ac6=0.f, ac7=0.f;
  #define TAP(jj, xx)                      \
    ac0 = fmaf(c.w[jj][0], (xx), ac0);     \
    ac1 = fmaf(c.w[jj][1], (xx), ac1);     \
    ac2 = fmaf(c.w[jj][2], (xx), ac2);     \
    ac3 = fmaf(c.w[jj][3], (xx), ac3);     \
    ac4 = fmaf(c.w[jj][4], (xx), ac4);     \
    ac5 = fmaf(c.w[jj][5], (xx), ac5);     \
    ac6 = fmaf(c.w[jj][6], (xx), ac6);     \
    ac7 = fmaf(c.w[jj][7], (xx), ac7);
  #pragma unroll
  for (int wg = 0; wg < 8; ++wg) {
    G2 v = rd8(16 * l + 16 + 8 * wg);
    const int j0 = 8 * wg;                 // constant after unroll
    TAP(j0 + 0, v.a.x); TAP(j0 + 1, v.a.y);
    TAP(j0 + 2, v.a.z); TAP(j0 + 3, v.a.w);
    TAP(j0 + 4, v.b.x); TAP(j0 + 5, v.b.y);
    TAP(j0 + 6, v.b.z); TAP(j0 + 7, v.b.w);
  }
  #undef TAP

  const float a10 = c.a1[0], a20 = c.a2[0];
  const float a11 = c.a1[1], a21 = c.a2[1];
  const float a12 = c.a1[2], a22 = c.a2[2];
  const float a13 = c.a1[3], a23 = c.a2[3];

  // transposed direct-form II states seeded by the predictor
  float z10=ac0, z20=ac1, z11=ac2, z21=ac3;
  float z12=ac4, z22=ac5, z13=ac6, z23=ac7;

  auto step = [&](float x0) -> float {
    float y0 = x0 + z10;
    z10 = fmaf(-a10, y0, fmaf(2.f, x0, z20));
    z20 = fmaf(-a20, y0, x0);
    float y1 = y0 + z11;
    z11 = fmaf(-a11, y1, fmaf(2.f, y0, z21));
    z21 = fmaf(-a21, y1, y0);
    float y2 = y1 + z12;
    z12 = fmaf(-a12, y2, fmaf(2.f, y1, z22));
    z22 = fmaf(-a22, y2, y1);
    float y3 = y2 + z13;
    z13 = fmaf(-a13, y3, fmaf(2.f, y2, z23));
    z23 = fmaf(-a23, y3, y2);
    return y3;
  };

  // ---- main: 16 inputs (forward descending) -> 32 outputs ----
  // input at local offset k yields forward outputs 2k+1 then 2k
  float o[32];                           // static indices only
  {
    float s;
    s = g1.b.w; o[31] = step(s); o[30] = step(s);
    s = g1.b.z; o[29] = step(s); o[28] = step(s);
    s = g1.b.y; o[27] = step(s); o[26] = step(s);
    s = g1.b.x; o[25] = step(s); o[24] = step(s);
    s = g1.a.w; o[23] = step(s); o[22] = step(s);
    s = g1.a.z; o[21] = step(s); o[20] = step(s);
    s = g1.a.y; o[19] = step(s); o[18] = step(s);
    s = g1.a.x; o[17] = step(s); o[16] = step(s);
    s = g0.b.w; o[15] = step(s); o[14] = step(s);
    s = g0.b.z; o[13] = step(s); o[12] = step(s);
    s = g0.b.y; o[11] = step(s); o[10] = step(s);
    s = g0.b.x; o[9]  = step(s); o[8]  = step(s);
    s = g0.a.w; o[7]  = step(s); o[6]  = step(s);
    s = g0.a.z; o[5]  = step(s); o[4]  = step(s);
    s = g0.a.y; o[3]  = step(s); o[2]  = step(s);
    s = g0.a.x; o[1]  = step(s); o[0]  = step(s);
  }

  // ---- flush: 2 half-wave rounds through L[0,1024) (input data dead) ----
  // Round r: lanes [32r,32r+32) deposit their 32 outputs; all lanes read
  // back lane-contiguous and store as 128B-dense runs. Same-wave DS pipe is
  // in-order; sched_barrier(0) pins compiler ordering across phases.
  float* yG = yrow + 2 * tbase;
  #pragma unroll
  for (int r = 0; r < 2; ++r) {
    if ((unsigned)(l - 32 * r) < 32u) {          // active half-wave writes
      const int cl = l - 32 * r;
      #pragma unroll
      for (int i = 0; i < 8; ++i) {
        int q = 32 * cl + 4 * i;
        *reinterpret_cast<float4*>(&lbuf[SWZ(q)]) =
            make_float4(o[4*i], o[4*i+1], o[4*i+2], o[4*i+3]);
      }
    }
    __builtin_amdgcn_sched_barrier(0);
    #pragma unroll
    for (int j = 0; j < 4; ++j) {                // all lanes read + store
      int local = 4 * l + 256 * j;               // 0..1023
      float4 v = *reinterpret_cast<const float4*>(&lbuf[SWZ(local)]);
      int c64 = 32 * r + (local >> 5);           // source chunk
      int m   = local & 31;                      // offset within chunk run
      *reinterpret_cast<float4*>(yG + 32 * c64 + m) = v;  // 128B dense
    }
    __builtin_amdgcn_sched_barrier(0);
  }
}

// ---------------- host side ----------------

// one filter step in double, state order z10,z20,z11,z21,z12,z22,z13,z23
static void step_d(double z[8], double xx, const double A1[4], const double A2[4]) {
  double u = xx;
  double v = u + z[0];
  double n0 = 2.0*u - A1[0]*v + z[1];
  double n1 = u - A2[0]*v;
  u = v; v = u + z[2];
  double n2 = 2.0*u - A1[1]*v + z[3];
  double n3 = u - A2[1]*v;
  u = v; v = u + z[4];
  double n4 = 2.0*u - A1[2]*v + z[5];
  double n5 = u - A2[2]*v;
  u = v; v = u + z[6];
  double n6 = 2.0*u - A1[3]*v + z[7];
  double n7 = u - A2[3]*v;
  z[0]=n0; z[1]=n1; z[2]=n2; z[3]=n3; z[4]=n4; z[5]=n5; z[6]=n6; z[7]=n7;
}

static void matvec8(const double A[8][8], const double v[8], double out[8]) {
  for (int r = 0; r < 8; ++r) {
    double s = 0.0;
    for (int k = 0; k < 8; ++k) s += A[r][k] * v[k];
    out[r] = s;
  }
}

// Replicates _cheby1_sos(8, 0.05, 0.5) and builds predictor taps.
static KArgs compute_args() {
  const int N = 8;
  const double rp = 0.05, Wn = 0.5;
  const double PI = 3.14159265358979323846;
  double eps = std::sqrt(std::pow(10.0, 0.1 * rp) - 1.0);
  double mu = std::asinh(1.0 / eps) / (double)N;
  std::complex<double> p[8];
  std::complex<double> prodNegP(1.0, 0.0);
  int idx = 0;
  for (int m = -N + 1; m < N; m += 2) {
    double theta = PI * (double)m / (2.0 * N);
    std::complex<double> pp = -std::sinh(std::complex<double>(mu, theta));
    p[idx++] = pp;
    prodNegP *= -pp;
  }
  double k = prodNegP.real();
  k /= std::sqrt(1.0 + eps * eps);          // even N
  const double fs = 2.0;
  double warped = 2.0 * fs * std::tan(PI * Wn / fs);
  for (int i = 0; i < 8; i++) p[i] *= warped;
  k *= std::pow(warped, (double)N);
  const double fs2 = 2.0 * fs;
  std::complex<double> prodDen(1.0, 0.0);
  for (int i = 0; i < 8; i++) prodDen *= (fs2 - p[i]);
  double kz = k * (1.0 / prodDen).real();

  KArgs c;
  double A1d[4], A2d[4];
  int s = 0;
  for (int i = 0; i < 8; i++) {
    std::complex<double> pz = (fs2 + p[i]) / (fs2 - p[i]);
    if (pz.imag() > 0.0) {                  // same selection order as numpy
      A1d[s] = -2.0 * pz.real();
      A2d[s] = std::norm(pz);               // |pz|^2
      c.a1[s] = (float)A1d[s];
      c.a2[s] = (float)A2d[s];
      s++;
    }
  }
  c.g = (float)kz;

  // build A (8x8) and b from the step function
  double A[8][8], bv[8];
  for (int i = 0; i < 8; ++i) {
    double z[8] = {0,0,0,0,0,0,0,0};
    z[i] = 1.0;
    step_d(z, 0.0, A1d, A2d);
    for (int r = 0; r < 8; ++r) A[r][i] = z[r];
  }
  {
    double z[8] = {0,0,0,0,0,0,0,0};
    step_d(z, 1.0, A1d, A2d);
    for (int r = 0; r < 8; ++r) bv[r] = z[r];
  }
  // w_0 = (A+I)b ; w_{j+1} = A^2 w_j
  double w[8], t[8];
  matvec8(A, bv, t);
  for (int r = 0; r < 8; ++r) w[r] = t[r] + bv[r];
  for (int j = 0; j < 64; ++j) {
    for (int r = 0; r < 8; ++r) c.w[j][r] = (float)w[r];
    matvec8(A, w, t);
    matvec8(A, t, w);
  }
  return c;
}

extern "C" void kernel_launch(void* const* d_in, const int* in_sizes, int n_in,
                              void* d_out, int out_size, void* d_ws, size_t ws_size,
                              hipStream_t stream) {
  const float* x = (const float*)d_in[0];
  float* y = (float*)d_out;
  KArgs c = compute_args();
  int rows = in_sizes[0] / 32768;   // 256
  // 32 single-wave tiles per row -> 8192 blocks of 64 threads
  cheby_up_kernel<<<32 * rows, 64, 0, stream>>>(x, y, c);
}

// Round 16
// 24.619 us; speedup vs baseline: 1.5345x; 1.0912x over previous
//
#include <hip/hip_runtime.h>
#include <cmath>
#include <complex>

// ChebyUpsample: x (256, 32768) f32 -> repeat x2 -> reverse -> cheby1(8,0.05,0.5)
// 4-biquad cascade -> reverse -> y (256, 65536) f32.
// R16 = R9-verified kernel (reversed-time chunked IIR, single-wave blocks,
// linear-predictor warm-up, 26.6us) + NON-TEMPORAL OUTPUT STORES:
//   output is write-once/never-read -> `nt` stores skip L2 write-allocate,
//   streaming toward HBM and leaving L2/L3 to the input (fills hit 6.7TB/s
//   store-only; our mixed path sat at ~3.6TB/s with normal stores).
//   Loads keep normal caching (L3 absorbs re-reads; FETCH ~17MB < 32MB input).
// Structure (verified R9): block = 1 wave = 64 chunks x 32 inputs; tile =
// 2048 (+64 halo) = 8448B LDS; 4096 blocks = 16/CU = 4 waves/SIMD. Zero
// barriers (single wave; DS pipe in-order). Predictor:
// z = sum_{j=0..63} w_j * staged[32l+32+j], w_j = A^{2j}(A+I)b (host double).
// Flush: per-wave transpose through the dead input region, 2 halves,
// 128B-dense nt stores. SWZ(q)=q^(((q>>6)&7)<<2): 16B-granular involution,
// identity in halo.

struct KArgs {
  float g;          // kz gain folded into staged input
  float a1[4];
  float a2[4];
  float w[64][8];   // state predictor taps, state order z10,z20,z11,...,z23
};

struct G2 { float4 a, b; };   // a = s[qq..qq+3], b = s[qq+4..qq+7]

typedef float f4nt __attribute__((ext_vector_type(4)));

#define SWZ(q) ((q) ^ ((((q) >> 6) & 7) << 2))

__global__ __launch_bounds__(64)
void cheby_up_kernel(const float* __restrict__ x, float* __restrict__ y, KArgs c) {
  constexpr int T_IN = 32768;
  constexpr int TILE = 2048;
  __shared__ __align__(16) float lbuf[TILE + 64];   // 8448 B

  const int row = blockIdx.x >> 4;
  const int tb  = blockIdx.x & 15;      // tile index within row
  const int l   = threadIdx.x;          // lane = chunk id, 0..63
  const float* xrow = x + (size_t)row * T_IN;
  float*       yrow = y + (size_t)row * (size_t)(2 * T_IN);
  const int tbase = TILE * tb;

  const float g = c.g;

  // ---- stage tile, coalesced, pre-scaled by g (8 x float4 per lane) ----
  #pragma unroll
  for (int j = 0; j < 8; ++j) {
    int q = 4 * l + 256 * j;                        // 0..2047
    float4 v = *reinterpret_cast<const float4*>(xrow + tbase + q);
    v.x *= g; v.y *= g; v.z *= g; v.w *= g;
    *reinterpret_cast<float4*>(&lbuf[SWZ(q)]) = v;
  }
  if (l < 16) {                                     // 64-float halo
    int q = TILE + 4 * l;                           // SWZ identity here
    int gi = tbase + q;
    float4 v = make_float4(0.f, 0.f, 0.f, 0.f);
    if (gi < T_IN) {
      v = *reinterpret_cast<const float4*>(xrow + gi);
      v.x *= g; v.y *= g; v.z *= g; v.w *= g;
    }
    *reinterpret_cast<float4*>(&lbuf[q]) = v;
  }
  // single wave: DS reads below are ordered after these writes (lgkmcnt)

  auto rd8 = [&](int qq) -> G2 {        // 8 consecutive staged samples
    G2 r;
    r.a = *reinterpret_cast<const float4*>(&lbuf[SWZ(qq)]);
    r.b = *reinterpret_cast<const float4*>(&lbuf[SWZ(qq + 4)]);
    return r;
  };

  // own 32 inputs -> registers (independent of warm region; issue early)
  G2 g3 = rd8(32 * l + 24);
  G2 g2 = rd8(32 * l + 16);
  G2 g1 = rd8(32 * l + 8);
  G2 g0 = rd8(32 * l);

  // ---- linear-predictor warm-up: z = sum_{j=0..63} w_j * staged[32l+32+j] ----
  float ac0=0.f, ac1=0.f, ac2=0.f, ac3=0.f, ac4=0.f, ac5=0.f, ac6=0.f, ac7=0.f;
  #define TAP(jj, xx)                      \
    ac0 = fmaf(c.w[jj][0], (xx), ac0);     \
    ac1 = fmaf(c.w[jj][1], (xx), ac1);     \
    ac2 = fmaf(c.w[jj][2], (xx), ac2);     \
    ac3 = fmaf(c.w[jj][3], (xx), ac3);     \
    ac4 = fmaf(c.w[jj][4], (xx), ac4);     \
    ac5 = fmaf(c.w[jj][5], (xx), ac5);     \
    ac6 = fmaf(c.w[jj][6], (xx), ac6);     \
    ac7 = fmaf(c.w[jj][7], (xx), ac7);
  #pragma unroll
  for (int wg = 0; wg < 8; ++wg) {
    G2 v = rd8(32 * l + 32 + 8 * wg);
    const int j0 = 8 * wg;                 // constant after unroll
    TAP(j0 + 0, v.a.x); TAP(j0 + 1, v.a.y);
    TAP(j0 + 2, v.a.z); TAP(j0 + 3, v.a.w);
    TAP(j0 + 4, v.b.x); TAP(j0 + 5, v.b.y);
    TAP(j0 + 6, v.b.z); TAP(j0 + 7, v.b.w);
  }
  #undef TAP

  const float a10 = c.a1[0], a20 = c.a2[0];
  const float a11 = c.a1[1], a21 = c.a2[1];
  const float a12 = c.a1[2], a22 = c.a2[2];
  const float a13 = c.a1[3], a23 = c.a2[3];

  // transposed direct-form II states seeded by the predictor
  float z10=ac0, z20=ac1, z11=ac2, z21=ac3;
  float z12=ac4, z22=ac5, z13=ac6, z23=ac7;

  auto step = [&](float x0) -> float {
    float y0 = x0 + z10;
    z10 = fmaf(-a10, y0, fmaf(2.f, x0, z20));
    z20 = fmaf(-a20, y0, x0);
    float y1 = y0 + z11;
    z11 = fmaf(-a11, y1, fmaf(2.f, y0, z21));
    z21 = fmaf(-a21, y1, y0);
    float y2 = y1 + z12;
    z12 = fmaf(-a12, y2, fmaf(2.f, y1, z22));
    z22 = fmaf(-a22, y2, y1);
    float y3 = y2 + z13;
    z13 = fmaf(-a13, y3, fmaf(2.f, y2, z23));
    z23 = fmaf(-a23, y3, y2);
    return y3;
  };

  float o[32];                // static indices only (fully unrolled)

  // per-wave transpose + NON-TEMPORAL store of 32 outputs at chunk offset half
  auto flush32 = [&](int half) {
    #pragma unroll
    for (int i = 0; i < 8; ++i) {
      int q = 32 * l + 4 * i;
      *reinterpret_cast<float4*>(&lbuf[SWZ(q)]) =
          make_float4(o[4*i], o[4*i+1], o[4*i+2], o[4*i+3]);
    }
    float* yG = yrow + 2 * tbase + half;
    #pragma unroll
    for (int j = 0; j < 8; ++j) {
      int local = 4 * l + 256 * j;                    // 0..2047
      f4nt v = *reinterpret_cast<const f4nt*>(&lbuf[SWZ(local)]);
      int c64 = local >> 5;                           // source chunk 0..63
      int m   = local & 31;                           // offset within half
      __builtin_nontemporal_store(
          v, reinterpret_cast<f4nt*>(yG + 64 * c64 + m));  // 128B dense, no L2 alloc
    }
  };

  // ---- phase A: outputs [32,64) from inputs [16,32) (forward descending) ----
  {
    float s;
    s = g3.b.w; o[31] = step(s); o[30] = step(s);
    s = g3.b.z; o[29] = step(s); o[28] = step(s);
    s = g3.b.y; o[27] = step(s); o[26] = step(s);
    s = g3.b.x; o[25] = step(s); o[24] = step(s);
    s = g3.a.w; o[23] = step(s); o[22] = step(s);
    s = g3.a.z; o[21] = step(s); o[20] = step(s);
    s = g3.a.y; o[19] = step(s); o[18] = step(s);
    s = g3.a.x; o[17] = step(s); o[16] = step(s);
    s = g2.b.w; o[15] = step(s); o[14] = step(s);
    s = g2.b.z; o[13] = step(s); o[12] = step(s);
    s = g2.b.y; o[11] = step(s); o[10] = step(s);
    s = g2.b.x; o[9]  = step(s); o[8]  = step(s);
    s = g2.a.w; o[7]  = step(s); o[6]  = step(s);
    s = g2.a.z; o[5]  = step(s); o[4]  = step(s);
    s = g2.a.y; o[3]  = step(s); o[2]  = step(s);
    s = g2.a.x; o[1]  = step(s); o[0]  = step(s);
  }
  flush32(32);

  // ---- phase B: outputs [0,32) from inputs [0,16) ----
  {
    float s;
    s = g1.b.w; o[31] = step(s); o[30] = step(s);
    s = g1.b.z; o[29] = step(s); o[28] = step(s);
    s = g1.b.y; o[27] = step(s); o[26] = step(s);
    s = g1.b.x; o[25] = step(s); o[24] = step(s);
    s = g1.a.w; o[23] = step(s); o[22] = step(s);
    s = g1.a.z; o[21] = step(s); o[20] = step(s);
    s = g1.a.y; o[19] = step(s); o[18] = step(s);
    s = g1.a.x; o[17] = step(s); o[16] = step(s);
    s = g0.b.w; o[15] = step(s); o[14] = step(s);
    s = g0.b.z; o[13] = step(s); o[12] = step(s);
    s = g0.b.y; o[11] = step(s); o[10] = step(s);
    s = g0.b.x; o[9]  = step(s); o[8]  = step(s);
    s = g0.a.w; o[7]  = step(s); o[6]  = step(s);
    s = g0.a.z; o[5]  = step(s); o[4]  = step(s);
    s = g0.a.y; o[3]  = step(s); o[2]  = step(s);
    s = g0.a.x; o[1]  = step(s); o[0]  = step(s);
  }
  flush32(0);
}

// ---------------- host side ----------------

// one filter step in double, state order z10,z20,z11,z21,z12,z22,z13,z23
static void step_d(double z[8], double xx, const double A1[4], const double A2[4]) {
  double u = xx;
  double v = u + z[0];
  double n0 = 2.0*u - A1[0]*v + z[1];
  double n1 = u - A2[0]*v;
  u = v; v = u + z[2];
  double n2 = 2.0*u - A1[1]*v + z[3];
  double n3 = u - A2[1]*v;
  u = v; v = u + z[4];
  double n4 = 2.0*u - A1[2]*v + z[5];
  double n5 = u - A2[2]*v;
  u = v; v = u + z[6];
  double n6 = 2.0*u - A1[3]*v + z[7];
  double n7 = u - A2[3]*v;
  z[0]=n0; z[1]=n1; z[2]=n2; z[3]=n3; z[4]=n4; z[5]=n5; z[6]=n6; z[7]=n7;
}

static void matvec8(const double A[8][8], const double v[8], double out[8]) {
  for (int r = 0; r < 8; ++r) {
    double s = 0.0;
    for (int k = 0; k < 8; ++k) s += A[r][k] * v[k];
    out[r] = s;
  }
}

// Replicates _cheby1_sos(8, 0.05, 0.5) and builds predictor taps.
static KArgs compute_args() {
  const int N = 8;
  const double rp = 0.05, Wn = 0.5;
  const double PI = 3.14159265358979323846;
  double eps = std::sqrt(std::pow(10.0, 0.1 * rp) - 1.0);
  double mu = std::asinh(1.0 / eps) / (double)N;
  std::complex<double> p[8];
  std::complex<double> prodNegP(1.0, 0.0);
  int idx = 0;
  for (int m = -N + 1; m < N; m += 2) {
    double theta = PI * (double)m / (2.0 * N);
    std::complex<double> pp = -std::sinh(std::complex<double>(mu, theta));
    p[idx++] = pp;
    prodNegP *= -pp;
  }
  double k = prodNegP.real();
  k /= std::sqrt(1.0 + eps * eps);          // even N
  const double fs = 2.0;
  double warped = 2.0 * fs * std::tan(PI * Wn / fs);
  for (int i = 0; i < 8; i++) p[i] *= warped;
  k *= std::pow(warped, (double)N);
  const double fs2 = 2.0 * fs;
  std::complex<double> prodDen(1.0, 0.0);
  for (int i = 0; i < 8; i++) prodDen *= (fs2 - p[i]);
  double kz = k * (1.0 / prodDen).real();

  KArgs c;
  double A1d[4], A2d[4];
  int s = 0;
  for (int i = 0; i < 8; i++) {
    std::complex<double> pz = (fs2 + p[i]) / (fs2 - p[i]);
    if (pz.imag() > 0.0) {                  // same selection order as numpy
      A1d[s] = -2.0 * pz.real();
      A2d[s] = std::norm(pz);               // |pz|^2
      c.a1[s] = (float)A1d[s];
      c.a2[s] = (float)A2d[s];
      s++;
    }
  }
  c.g = (float)kz;

  // build A (8x8) and b from the step function
  double A[8][8], bv[8];
  for (int i = 0; i < 8; ++i) {
    double z[8] = {0,0,0,0,0,0,0,0};
    z[i] = 1.0;
    step_d(z, 0.0, A1d, A2d);
    for (int r = 0; r < 8; ++r) A[r][i] = z[r];
  }
  {
    double z[8] = {0,0,0,0,0,0,0,0};
    step_d(z, 1.0, A1d, A2d);
    for (int r = 0; r < 8; ++r) bv[r] = z[r];
  }
  // w_0 = (A+I)b ; w_{j+1} = A^2 w_j
  double w[8], t[8];
  matvec8(A, bv, t);
  for (int r = 0; r < 8; ++r) w[r] = t[r] + bv[r];
  for (int j = 0; j < 64; ++j) {
    for (int r = 0; r < 8; ++r) c.w[j][r] = (float)w[r];
    matvec8(A, w, t);
    matvec8(A, t, w);
  }
  return c;
}

extern "C" void kernel_launch(void* const* d_in, const int* in_sizes, int n_in,
                              void* d_out, int out_size, void* d_ws, size_t ws_size,
                              hipStream_t stream) {
  const float* x = (const float*)d_in[0];
  float* y = (float*)d_out;
  KArgs c = compute_args();
  int rows = in_sizes[0] / 32768;   // 256
  // 16 single-wave tiles per row -> 4096 blocks of 64 threads
  cheby_up_kernel<<<16 * rows, 64, 0, stream>>>(x, y, c);
}

// Round 17
// 22.750 us; speedup vs baseline: 1.6606x; 1.0822x over previous
//
#include <hip/hip_runtime.h>
#include <cmath>
#include <complex>

// ChebyUpsample: x (256, 32768) f32 -> repeat x2 -> reverse -> cheby1(8,0.05,0.5)
// 4-biquad cascade -> reverse -> y (256, 65536) f32.
// R17 = R15 (high-occupancy: chunk=16, tile=1024+64, 4.35KB LDS, 8192
// single-wave blocks -> ~6 waves/SIMD, verified pass @26.9) composed with
// R16's NON-TEMPORAL OUTPUT STORES (verified pass @24.6). Theory: R15's
// extra TLP was null only because L2-allocating stores serialized the write
// path; with nt stores streaming to HBM, additional waves/SIMD can fill the
// memory-wait gaps.
// Predictor: z = sum_{j=0..63} w_j * staged[16l+16+j], w_j = A^{2j}(A+I)b
// (host double; staged pre-scaled by g). Flush: 2 half-wave rounds through
// L[0,1024), 128B-dense nt stores. SWZ(q)=q^(((q>>6)&7)<<2): 16B-granular
// involution, identity in halo [1024,1088). Zero barriers (single wave).

struct KArgs {
  float g;          // kz gain folded into staged input
  float a1[4];
  float a2[4];
  float w[64][8];   // state predictor taps, state order z10,z20,z11,...,z23
};

struct G2 { float4 a, b; };   // a = s[qq..qq+3], b = s[qq+4..qq+7]

typedef float f4nt __attribute__((ext_vector_type(4)));

#define SWZ(q) ((q) ^ ((((q) >> 6) & 7) << 2))

__global__ __launch_bounds__(64)
void cheby_up_kernel(const float* __restrict__ x, float* __restrict__ y, KArgs c) {
  constexpr int T_IN = 32768;
  constexpr int TILE = 1024;
  __shared__ __align__(16) float lbuf[TILE + 64];   // 4352 B

  const int row = blockIdx.x >> 5;
  const int tb  = blockIdx.x & 31;      // tile index within row, 0..31
  const int l   = threadIdx.x;          // lane = chunk id, 0..63
  const float* xrow = x + (size_t)row * T_IN;
  float*       yrow = y + (size_t)row * (size_t)(2 * T_IN);
  const int tbase = TILE * tb;

  const float g = c.g;

  // ---- stage tile, coalesced, pre-scaled by g (4 x float4 per lane) ----
  #pragma unroll
  for (int j = 0; j < 4; ++j) {
    int q = 4 * l + 256 * j;                        // 0..1023
    float4 v = *reinterpret_cast<const float4*>(xrow + tbase + q);
    v.x *= g; v.y *= g; v.z *= g; v.w *= g;
    *reinterpret_cast<float4*>(&lbuf[SWZ(q)]) = v;
  }
  if (l < 16) {                                     // 64-float halo
    int q = TILE + 4 * l;                           // 1024..1087, SWZ identity
    int gi = tbase + q;
    float4 v = make_float4(0.f, 0.f, 0.f, 0.f);
    if (gi < T_IN) {
      v = *reinterpret_cast<const float4*>(xrow + gi);
      v.x *= g; v.y *= g; v.z *= g; v.w *= g;
    }
    *reinterpret_cast<float4*>(&lbuf[q]) = v;
  }
  // single wave: DS reads below are ordered after these writes (lgkmcnt)

  auto rd8 = [&](int qq) -> G2 {        // 8 consecutive staged samples
    G2 v;
    v.a = *reinterpret_cast<const float4*>(&lbuf[SWZ(qq)]);
    v.b = *reinterpret_cast<const float4*>(&lbuf[SWZ(qq + 4)]);
    return v;
  };

  // own 16 inputs -> registers (issued before taps; independent)
  G2 g1 = rd8(16 * l + 8);
  G2 g0 = rd8(16 * l);

  // ---- linear-predictor warm-up over staged[16l+16 .. 16l+80) ----
  float ac0=0.f, ac1=0.f, ac2=0.f, ac3=0.f, ac4=0.f, ac5=0.f, ac6=0.f, ac7=0.f;
  #define TAP(jj, xx)                      \
    ac0 = fmaf(c.w[jj][0], (xx), ac0);     \
    ac1 = fmaf(c.w[jj][1], (xx), ac1);     \
    ac2 = fmaf(c.w[jj][2], (xx), ac2);     \
    ac3 = fmaf(c.w[jj][3], (xx), ac3);     \
    ac4 = fmaf(c.w[jj][4], (xx), ac4);     \
    ac5 = fmaf(c.w[jj][5], (xx), ac5);     \
    ac6 = fmaf(c.w[jj][6], (xx), ac6);     \
    ac7 = fmaf(c.w[jj][7], (xx), ac7);
  #pragma unroll
  for (int wg = 0; wg < 8; ++wg) {
    G2 v = rd8(16 * l + 16 + 8 * wg);
    const int j0 = 8 * wg;                 // constant after unroll
    TAP(j0 + 0, v.a.x); TAP(j0 + 1, v.a.y);
    TAP(j0 + 2, v.a.z); TAP(j0 + 3, v.a.w);
    TAP(j0 + 4, v.b.x); TAP(j0 + 5, v.b.y);
    TAP(j0 + 6, v.b.z); TAP(j0 + 7, v.b.w);
  }
  #undef TAP

  const float a10 = c.a1[0], a20 = c.a2[0];
  const float a11 = c.a1[1], a21 = c.a2[1];
  const float a12 = c.a1[2], a22 = c.a2[2];
  const float a13 = c.a1[3], a23 = c.a2[3];

  // transposed direct-form II states seeded by the predictor
  float z10=ac0, z20=ac1, z11=ac2, z21=ac3;
  float z12=ac4, z22=ac5, z13=ac6, z23=ac7;

  auto step = [&](float x0) -> float {
    float y0 = x0 + z10;
    z10 = fmaf(-a10, y0, fmaf(2.f, x0, z20));
    z20 = fmaf(-a20, y0, x0);
    float y1 = y0 + z11;
    z11 = fmaf(-a11, y1, fmaf(2.f, y0, z21));
    z21 = fmaf(-a21, y1, y0);
    float y2 = y1 + z12;
    z12 = fmaf(-a12, y2, fmaf(2.f, y1, z22));
    z22 = fmaf(-a22, y2, y1);
    float y3 = y2 + z13;
    z13 = fmaf(-a13, y3, fmaf(2.f, y2, z23));
    z23 = fmaf(-a23, y3, y2);
    return y3;
  };

  // ---- main: 16 inputs (forward descending) -> 32 outputs ----
  // input at local offset k yields forward outputs 2k+1 then 2k
  float o[32];                           // static indices only
  {
    float s;
    s = g1.b.w; o[31] = step(s); o[30] = step(s);
    s = g1.b.z; o[29] = step(s); o[28] = step(s);
    s = g1.b.y; o[27] = step(s); o[26] = step(s);
    s = g1.b.x; o[25] = step(s); o[24] = step(s);
    s = g1.a.w; o[23] = step(s); o[22] = step(s);
    s = g1.a.z; o[21] = step(s); o[20] = step(s);
    s = g1.a.y; o[19] = step(s); o[18] = step(s);
    s = g1.a.x; o[17] = step(s); o[16] = step(s);
    s = g0.b.w; o[15] = step(s); o[14] = step(s);
    s = g0.b.z; o[13] = step(s); o[12] = step(s);
    s = g0.b.y; o[11] = step(s); o[10] = step(s);
    s = g0.b.x; o[9]  = step(s); o[8]  = step(s);
    s = g0.a.w; o[7]  = step(s); o[6]  = step(s);
    s = g0.a.z; o[5]  = step(s); o[4]  = step(s);
    s = g0.a.y; o[3]  = step(s); o[2]  = step(s);
    s = g0.a.x; o[1]  = step(s); o[0]  = step(s);
  }

  // ---- flush: 2 half-wave rounds through L[0,1024) (input data dead) ----
  // Round r: lanes [32r,32r+32) deposit their 32 outputs; all lanes read
  // back lane-contiguous and nt-store as 128B-dense runs. Same-wave DS pipe
  // is in-order; sched_barrier(0) pins compiler ordering across phases.
  float* yG = yrow + 2 * tbase;
  #pragma unroll
  for (int r = 0; r < 2; ++r) {
    if ((unsigned)(l - 32 * r) < 32u) {          // active half-wave writes
      const int cl = l - 32 * r;
      #pragma unroll
      for (int i = 0; i < 8; ++i) {
        int q = 32 * cl + 4 * i;
        *reinterpret_cast<float4*>(&lbuf[SWZ(q)]) =
            make_float4(o[4*i], o[4*i+1], o[4*i+2], o[4*i+3]);
      }
    }
    __builtin_amdgcn_sched_barrier(0);
    #pragma unroll
    for (int j = 0; j < 4; ++j) {                // all lanes read + store
      int local = 4 * l + 256 * j;               // 0..1023
      f4nt v = *reinterpret_cast<const f4nt*>(&lbuf[SWZ(local)]);
      int c64 = 32 * r + (local >> 5);           // source chunk
      int m   = local & 31;                      // offset within chunk run
      __builtin_nontemporal_store(
          v, reinterpret_cast<f4nt*>(yG + 32 * c64 + m));  // 128B dense, no L2
    }
    __builtin_amdgcn_sched_barrier(0);
  }
}

// ---------------- host side ----------------

// one filter step in double, state order z10,z20,z11,z21,z12,z22,z13,z23
static void step_d(double z[8], double xx, const double A1[4], const double A2[4]) {
  double u = xx;
  double v = u + z[0];
  double n0 = 2.0*u - A1[0]*v + z[1];
  double n1 = u - A2[0]*v;
  u = v; v = u + z[2];
  double n2 = 2.0*u - A1[1]*v + z[3];
  double n3 = u - A2[1]*v;
  u = v; v = u + z[4];
  double n4 = 2.0*u - A1[2]*v + z[5];
  double n5 = u - A2[2]*v;
  u = v; v = u + z[6];
  double n6 = 2.0*u - A1[3]*v + z[7];
  double n7 = u - A2[3]*v;
  z[0]=n0; z[1]=n1; z[2]=n2; z[3]=n3; z[4]=n4; z[5]=n5; z[6]=n6; z[7]=n7;
}

static void matvec8(const double A[8][8], const double v[8], double out[8]) {
  for (int r = 0; r < 8; ++r) {
    double s = 0.0;
    for (int k = 0; k < 8; ++k) s += A[r][k] * v[k];
    out[r] = s;
  }
}

// Replicates _cheby1_sos(8, 0.05, 0.5) and builds predictor taps.
static KArgs compute_args() {
  const int N = 8;
  const double rp = 0.05, Wn = 0.5;
  const double PI = 3.14159265358979323846;
  double eps = std::sqrt(std::pow(10.0, 0.1 * rp) - 1.0);
  double mu = std::asinh(1.0 / eps) / (double)N;
  std::complex<double> p[8];
  std::complex<double> prodNegP(1.0, 0.0);
  int idx = 0;
  for (int m = -N + 1; m < N; m += 2) {
    double theta = PI * (double)m / (2.0 * N);
    std::complex<double> pp = -std::sinh(std::complex<double>(mu, theta));
    p[idx++] = pp;
    prodNegP *= -pp;
  }
  double k = prodNegP.real();
  k /= std::sqrt(1.0 + eps * eps);          // even N
  const double fs = 2.0;
  double warped = 2.0 * fs * std::tan(PI * Wn / fs);
  for (int i = 0; i < 8; i++) p[i] *= warped;
  k *= std::pow(warped, (double)N);
  const double fs2 = 2.0 * fs;
  std::complex<double> prodDen(1.0, 0.0);
  for (int i = 0; i < 8; i++) prodDen *= (fs2 - p[i]);
  double kz = k * (1.0 / prodDen).real();

  KArgs c;
  double A1d[4], A2d[4];
  int s = 0;
  for (int i = 0; i < 8; i++) {
    std::complex<double> pz = (fs2 + p[i]) / (fs2 - p[i]);
    if (pz.imag() > 0.0) {                  // same selection order as numpy
      A1d[s] = -2.0 * pz.real();
      A2d[s] = std::norm(pz);               // |pz|^2
      c.a1[s] = (float)A1d[s];
      c.a2[s] = (float)A2d[s];
      s++;
    }
  }
  c.g = (float)kz;

  // build A (8x8) and b from the step function
  double A[8][8], bv[8];
  for (int i = 0; i < 8; ++i) {
    double z[8] = {0,0,0,0,0,0,0,0};
    z[i] = 1.0;
    step_d(z, 0.0, A1d, A2d);
    for (int r = 0; r < 8; ++r) A[r][i] = z[r];
  }
  {
    double z[8] = {0,0,0,0,0,0,0,0};
    step_d(z, 1.0, A1d, A2d);
    for (int r = 0; r < 8; ++r) bv[r] = z[r];
  }
  // w_0 = (A+I)b ; w_{j+1} = A^2 w_j
  double w[8], t[8];
  matvec8(A, bv, t);
  for (int r = 0; r < 8; ++r) w[r] = t[r] + bv[r];
  for (int j = 0; j < 64; ++j) {
    for (int r = 0; r < 8; ++r) c.w[j][r] = (float)w[r];
    matvec8(A, w, t);
    matvec8(A, t, w);
  }
  return c;
}

extern "C" void kernel_launch(void* const* d_in, const int* in_sizes, int n_in,
                              void* d_out, int out_size, void* d_ws, size_t ws_size,
                              hipStream_t stream) {
  const float* x = (const float*)d_in[0];
  float* y = (float*)d_out;
  KArgs c = compute_args();
  int rows = in_sizes[0] / 32768;   // 256
  // 32 single-wave tiles per row -> 8192 blocks of 64 threads
  cheby_up_kernel<<<32 * rows, 64, 0, stream>>>(x, y, c);
}